// Round 7
// baseline (1427.981 us; speedup 1.0000x reference)
//
#include <hip/hip_runtime.h>
#include <hip/hip_bf16.h>
#include <stdint.h>

// Problem constants
#define BB 4
#define TT 4096
#define DD 2048
#define MM (BB*TT)   // 16384 rows
#define WC 64        // wkv chunks per sequence
#define WL 64        // wkv chunk length (WC*WL == TT)

typedef __bf16 bf16x8 __attribute__((ext_vector_type(8)));
typedef float  f32x4  __attribute__((ext_vector_type(4)));

__device__ __forceinline__ void g2l16(const void* g, void* l) {
  __builtin_amdgcn_global_load_lds(
      (const __attribute__((address_space(1))) void*)g,
      (__attribute__((address_space(3))) void*)l,
      16, 0, 0);
}

// ---------------------------------------------------------------------------
// Kernel 0: dtype detect + convert small vectors to fp32.
// ---------------------------------------------------------------------------
__global__ void detect_small_kernel(const void* __restrict__ tdec_raw,
                                    const void* __restrict__ tfirst_raw,
                                    const void* __restrict__ lng_raw,
                                    const void* __restrict__ lnb_raw,
                                    const void* __restrict__ tmk_raw,
                                    const void* __restrict__ tmv_raw,
                                    const void* __restrict__ tmr_raw,
                                    int* __restrict__ flag,
                                    float* __restrict__ tdecF,
                                    float* __restrict__ tfirstF,
                                    float* __restrict__ lngF,
                                    float* __restrict__ lnbF,
                                    float* __restrict__ tmkF,
                                    float* __restrict__ tmvF,
                                    float* __restrict__ tmrF)
{
  const uint32_t w0 = *(const uint32_t*)tdec_raw;
  const int isf32 = ((w0 & 0xFFFFu) == 0u) ? 1 : 0;
  if (threadIdx.x == 0) *flag = isf32;
  for (int d = threadIdx.x; d < DD; d += blockDim.x) {
    if (isf32) {
      tdecF[d]   = ((const float*)tdec_raw)[d];
      tfirstF[d] = ((const float*)tfirst_raw)[d];
      lngF[d]    = ((const float*)lng_raw)[d];
      lnbF[d]    = ((const float*)lnb_raw)[d];
      tmkF[d]    = ((const float*)tmk_raw)[d];
      tmvF[d]    = ((const float*)tmv_raw)[d];
      tmrF[d]    = ((const float*)tmr_raw)[d];
    } else {
      tdecF[d]   = (float)((const __bf16*)tdec_raw)[d];
      tfirstF[d] = (float)((const __bf16*)tfirst_raw)[d];
      lngF[d]    = (float)((const __bf16*)lng_raw)[d];
      lnbF[d]    = (float)((const __bf16*)lnb_raw)[d];
      tmkF[d]    = (float)((const __bf16*)tmk_raw)[d];
      tmvF[d]    = (float)((const __bf16*)tmv_raw)[d];
      tmrF[d]    = (float)((const __bf16*)tmr_raw)[d];
    }
  }
}

// ---------------------------------------------------------------------------
// Kernel 0b: convert one DxD weight matrix to canonical bf16
// ---------------------------------------------------------------------------
__global__ void convert_w_kernel(const void* __restrict__ src,
                                 __bf16* __restrict__ dst,
                                 const int* __restrict__ flagp)
{
  const int isf32 = *flagp;
  const int64_t NV = (int64_t)DD * DD / 8;
  for (int64_t v = blockIdx.x * (int64_t)blockDim.x + threadIdx.x;
       v < NV; v += (int64_t)gridDim.x * blockDim.x) {
    const int64_t i = v * 8;
    bf16x8 o;
    if (isf32) {
      const float* sf = (const float*)src;
      f32x4 a = *(const f32x4*)(sf + i);
      f32x4 b = *(const f32x4*)(sf + i + 4);
      #pragma unroll
      for (int e = 0; e < 4; e++) { o[e] = (__bf16)a[e]; o[e+4] = (__bf16)b[e]; }
    } else {
      o = *(const bf16x8*)((const __bf16*)src + i);
    }
    *(bf16x8*)(dst + i) = o;
  }
}

// ---------------------------------------------------------------------------
// Kernel 1: token-shift mix -> xk, xv, xr (bf16)
// ---------------------------------------------------------------------------
__global__ void mix_kernel(const void* __restrict__ xraw,
                           const float* __restrict__ tmkF,
                           const float* __restrict__ tmvF,
                           const float* __restrict__ tmrF,
                           const int* __restrict__ flagp,
                           __bf16* __restrict__ xk,
                           __bf16* __restrict__ xv,
                           __bf16* __restrict__ xr)
{
  const int isf32 = *flagp;
  const int64_t NV = (int64_t)MM * DD / 8;
  for (int64_t v = blockIdx.x * (int64_t)blockDim.x + threadIdx.x;
       v < NV; v += (int64_t)gridDim.x * blockDim.x) {
    const int64_t i = v * 8;
    const int d = (int)(i & (DD - 1));
    const int64_t td = i & ((int64_t)TT * DD - 1);
    const bool has_prev = (td >= DD);
    float xc[8], xp[8];
    if (isf32) {
      const float* xf = (const float*)xraw;
      f32x4 a = *(const f32x4*)(xf + i);
      f32x4 b = *(const f32x4*)(xf + i + 4);
      #pragma unroll
      for (int e = 0; e < 4; e++) { xc[e] = a[e]; xc[e+4] = b[e]; }
      if (has_prev) {
        f32x4 c = *(const f32x4*)(xf + i - DD);
        f32x4 dd4 = *(const f32x4*)(xf + i - DD + 4);
        #pragma unroll
        for (int e = 0; e < 4; e++) { xp[e] = c[e]; xp[e+4] = dd4[e]; }
      } else {
        #pragma unroll
        for (int e = 0; e < 8; e++) xp[e] = 0.f;
      }
    } else {
      const __bf16* xb = (const __bf16*)xraw;
      bf16x8 a = *(const bf16x8*)(xb + i);
      #pragma unroll
      for (int e = 0; e < 8; e++) xc[e] = (float)a[e];
      if (has_prev) {
        bf16x8 c = *(const bf16x8*)(xb + i - DD);
        #pragma unroll
        for (int e = 0; e < 8; e++) xp[e] = (float)c[e];
      } else {
        #pragma unroll
        for (int e = 0; e < 8; e++) xp[e] = 0.f;
      }
    }
    bf16x8 ok, ov, orr;
    #pragma unroll
    for (int e = 0; e < 8; e++) {
      const float diff = xc[e] - xp[e];
      ok[e]  = (__bf16)(xp[e] + tmkF[d + e] * diff);
      ov[e]  = (__bf16)(xp[e] + tmvF[d + e] * diff);
      orr[e] = (__bf16)(xp[e] + tmrF[d + e] * diff);
    }
    *(bf16x8*)(xk + i) = ok;
    *(bf16x8*)(xv + i) = ov;
    *(bf16x8*)(xr + i) = orr;
  }
}

// ---------------------------------------------------------------------------
// Kernel 2: GEMM  C[m,n] = sum_k A[m,k] * Bm[n,k]   (B^T layout, bf16 MFMA)
//
// Round-7: r3's derived-waits 256x256/BK=64 schedule (best measured, 174us,
// 0 conflicts) with 16 WAVES (4Mx4N, 1024 thr) instead of 8. Diagnosis: all
// prior rounds idle the matrix pipe at 31-34% because each SIMD hosts only
// 2-3 waves; one 16x16x32 MFMA issues per ~5cyc, so a SIMD needs ~4
// MFMA-issuing waves to keep the pipe fed. 16 waves/block = 4/SIMD — the
// unexplored cell (r5/6's 3/SIMD was confounded by a smaller per-phase MFMA
// cluster and 1.33x more LDS traffic/FLOP). Per-wave tile 64x64 -> acc =
// 64 VGPR; total est ~124 < the 128-reg cap of launch_bounds(1024,4).
// Accumulation order over K identical to all prior rounds -> C bitwise same.
//
// LDS: 128 KiB = 2 bufs x (A 256x64 | B 256x64) bf16; buf p at elem p*32768,
// B at +16384. Swizzle (both-sides, 0-conflict proven r1/r3): 16B chunk c of
// row r (128B rows -> row bits don't alias bank bits) stored at chunk
// c^(r&7); inverse-swizzled per-lane global source; ds_read XORs the same.
//
// Staging: 1024 threads stage one 128-row half (16 KiB) per g2l call:
// thread -> row tid>>3, phys chunk tid&7, global chunk (tid&7)^(row&7);
// LDS dest = wave-uniform base + lane*16B (linear) — g2l semantics OK.
//
// Per tile t (CB = buf[t&1], OB = other), r3 schedule:
//   RD a0,b0,b1 (12 ds_reads)        liveness: a0+b0+b1 = 48 VGPR
//   stage (t+1).A -> OB (2 g2l)
//   Q1 (a0*b0, 8 MFMA), Q2 (a0*b1, 8)
//   sched_barrier; RD a1 (4 reads)
//   lgkmcnt(4); barrier              <- WAR cert: B-region reads done
//   stage (t+2).B -> CB (2 g2l)      (region certified free)
//   Q3 (a1*b1, 8), Q4 (a1*b0, 8)
//   vmcnt(2); barrier                <- FIFO: drains t+1.B then t+1.A,
//                                       leaves t+2.B's 2 loads in flight
// Invariant: entering tile t, buf[t&1] resident, exactly (t+1).B (2 loads)
// outstanding. Never vmcnt(0) in loop. Kd == 2048 -> 32 tiles everywhere.
// ---------------------------------------------------------------------------
#define BARX()   __builtin_amdgcn_s_barrier()
#define SCHEDB() __builtin_amdgcn_sched_barrier(0)
#define WAITL(n) asm volatile("s_waitcnt lgkmcnt(" #n ")" ::: "memory")
#define WAITV(n) asm volatile("s_waitcnt vmcnt(" #n ")" ::: "memory")

// stage half h (128 rows) of A/B K-tile kt into buf at elem offset PB
#define STG_A(PB, h, kt) \
    g2l16(Asrc + (size_t)((h)*128) * Kd + (size_t)(kt)*64, \
          smem + (PB) + (h)*8192 + tid*8)
#define STG_B(PB, h, kt) \
    g2l16(Bsrc + (size_t)((h)*128) * Kd + (size_t)(kt)*64, \
          smem + (PB) + 16384 + (h)*8192 + tid*8)

#define RD_A0(pb) do { _Pragma("unroll") for (int i_ = 0; i_ < 2; i_++) { \
    a0[i_][0] = *(const bf16x8*)(smem + (pb) + (aoff0 + i_*1024)); \
    a0[i_][1] = *(const bf16x8*)(smem + (pb) + ((aoff0 + i_*1024) ^ 32)); } } while (0)
#define RD_A1(pb) do { _Pragma("unroll") for (int i_ = 0; i_ < 2; i_++) { \
    a1[i_][0] = *(const bf16x8*)(smem + (pb) + (aoff0 + (i_+2)*1024)); \
    a1[i_][1] = *(const bf16x8*)(smem + (pb) + ((aoff0 + (i_+2)*1024) ^ 32)); } } while (0)
#define RD_B0(pb) do { _Pragma("unroll") for (int j_ = 0; j_ < 2; j_++) { \
    b0[j_][0] = *(const bf16x8*)(smem + (pb) + (boff0 + j_*1024)); \
    b0[j_][1] = *(const bf16x8*)(smem + (pb) + ((boff0 + j_*1024) ^ 32)); } } while (0)
#define RD_B1(pb) do { _Pragma("unroll") for (int j_ = 0; j_ < 2; j_++) { \
    b1[j_][0] = *(const bf16x8*)(smem + (pb) + (boff0 + (j_+2)*1024)); \
    b1[j_][1] = *(const bf16x8*)(smem + (pb) + ((boff0 + (j_+2)*1024) ^ 32)); } } while (0)

#define MFMA8(af, bf, IO, JO) do { \
    _Pragma("unroll") for (int i_ = 0; i_ < 2; i_++) { \
    _Pragma("unroll") for (int j_ = 0; j_ < 2; j_++) { \
      acc[(IO)+i_][(JO)+j_] = __builtin_amdgcn_mfma_f32_16x16x32_bf16((af)[i_][0], (bf)[j_][0], acc[(IO)+i_][(JO)+j_], 0, 0, 0); \
      acc[(IO)+i_][(JO)+j_] = __builtin_amdgcn_mfma_f32_16x16x32_bf16((af)[i_][1], (bf)[j_][1], acc[(IO)+i_][(JO)+j_], 0, 0, 0); \
    } } } while (0)

#define TILE16(CB, OB, tA, tB) do { \
    RD_A0(CB); RD_B0(CB); RD_B1(CB); \
    STG_A(OB, 0, tA); STG_A(OB, 1, tA); \
    __builtin_amdgcn_s_setprio(1); \
    MFMA8(a0, b0, 0, 0); \
    MFMA8(a0, b1, 0, 2); \
    __builtin_amdgcn_s_setprio(0); \
    SCHEDB(); \
    RD_A1(CB); \
    WAITL(4); \
    BARX(); \
    SCHEDB(); \
    STG_B(CB, 0, tB); STG_B(CB, 1, tB); \
    __builtin_amdgcn_s_setprio(1); \
    MFMA8(a1, b1, 2, 2); \
    MFMA8(a1, b0, 2, 0); \
    __builtin_amdgcn_s_setprio(0); \
    WAITV(2); \
    BARX(); \
    SCHEDB(); \
  } while (0)

// EPI: 0 = f32 store, 1 = final (flag ? f32 : bf16), 2 = sigmoid->bf16,
//      3 = bf16 store
template <int EPI>
__global__ void __launch_bounds__(1024, 4)
gemm_bt(const __bf16* __restrict__ A,
        const __bf16* __restrict__ Bm,
        void* __restrict__ Cout,
        const int* __restrict__ flagp,
        int Md, int Nd, int Kd)
{
  __shared__ __bf16 smem[65536];   // 128 KiB
  const int isf32 = (EPI == 1) ? *flagp : 0;
  const int tid  = threadIdx.x;    // 0..1023
  const int lane = tid & 63;
  const int wv   = tid >> 6;       // 0..15
  const int wm   = wv >> 2;        // wave row 0..3 (64 rows each)
  const int wn   = wv & 3;         // wave col 0..3 (64 cols each)
  const int l16  = lane & 15;
  const int qd   = lane >> 4;

  // XCD-aware mapping (Nd == 2048 -> 8 col-blocks == 8 XCDs).
  const int bid    = blockIdx.x;
  const int colblk = bid & 7;
  const int rowblk = bid >> 3;
  const int row0   = rowblk * 256;
  const int col0   = colblk * 256;

  // staging: thread -> row tid>>3, chunk (tid&7)^(row&7) on the global side
  const int srow   = tid >> 3;            // 0..127
  const int schunk = (tid & 7) ^ (srow & 7);
  const __bf16* Asrc = A  + (size_t)(row0 + srow) * Kd + schunk * 8;
  const __bf16* Bsrc = Bm + (size_t)(col0 + srow) * Kd + schunk * 8;

  // ds_read bases: fragment rows wm*64 + i*16 + l16 -> row&7 == l16&7;
  // kk=0 chunk = qd, kk=1 chunk = qd^4 (the ^32-elem trick, as r1/r3)
  const int c0    = (qd ^ (l16 & 7)) * 8;
  const int aoff0 = (wm * 64 + l16) * 64 + c0;
  const int boff0 = 16384 + (wn * 64 + l16) * 64 + c0;

  f32x4 acc[4][4];
  #pragma unroll
  for (int i = 0; i < 4; i++)
    #pragma unroll
    for (int j = 0; j < 4; j++)
      acc[i][j] = (f32x4){0.f, 0.f, 0.f, 0.f};

  bf16x8 a0[2][2], a1[2][2], b0[2][2], b1[2][2];

  // Prologue: tile0 A+B -> buf0, tile1 B -> buf1; vmcnt(2) leaves tile1.B
  // (2 loads) in flight = steady-state invariant.
  STG_A(0, 0, 0); STG_A(0, 1, 0);
  STG_B(0, 0, 0); STG_B(0, 1, 0);
  STG_B(32768, 0, 1); STG_B(32768, 1, 1);
  WAITV(2);
  BARX();
  SCHEDB();

  // 32 K-tiles. Main loop tiles 0..29 (stages A(1..30), B(2..31)); tail 30,31.
  #pragma unroll 1
  for (int it = 0; it < 15; ++it) {
    const int t = it << 1;
    TILE16(0,     32768, t + 1, t + 2);
    TILE16(32768, 0,     t + 2, t + 3);
  }

  // tile 30 (buf0): stage only tile31.A; drain fully at the end.
  {
    RD_A0(0); RD_B0(0); RD_B1(0);
    STG_A(32768, 0, 31); STG_A(32768, 1, 31);
    __builtin_amdgcn_s_setprio(1);
    MFMA8(a0, b0, 0, 0);
    MFMA8(a0, b1, 0, 2);
    __builtin_amdgcn_s_setprio(0);
    SCHEDB();
    RD_A1(0);
    __builtin_amdgcn_s_setprio(1);
    MFMA8(a1, b1, 2, 2);
    MFMA8(a1, b0, 2, 0);
    __builtin_amdgcn_s_setprio(0);
    WAITV(0);
    BARX();
    SCHEDB();
  }
  // tile 31 (buf1): no staging, no barriers.
  {
    RD_A0(32768); RD_B0(32768); RD_B1(32768);
    __builtin_amdgcn_s_setprio(1);
    MFMA8(a0, b0, 0, 0);
    MFMA8(a0, b1, 0, 2);
    __builtin_amdgcn_s_setprio(0);
    SCHEDB();
    RD_A1(32768);
    __builtin_amdgcn_s_setprio(1);
    MFMA8(a1, b1, 2, 2);
    MFMA8(a1, b0, 2, 0);
    __builtin_amdgcn_s_setprio(0);
  }

  // epilogue: C/D layout col=lane&15, row=quad*4+reg (verified m89/m91)
  #pragma unroll
  for (int i = 0; i < 4; i++) {
    const int rb = row0 + wm * 64 + i * 16 + qd * 4;
    #pragma unroll
    for (int j = 0; j < 4; j++) {
      const int c = col0 + wn * 64 + j * 16 + l16;
      #pragma unroll
      for (int reg = 0; reg < 4; reg++) {
        const size_t idx = (size_t)(rb + reg) * Nd + c;
        float v = acc[i][j][reg];
        if (EPI == 0) {
          ((float*)Cout)[idx] = v;
        } else if (EPI == 1) {
          if (isf32) ((float*)Cout)[idx] = v;
          else       ((__bf16*)Cout)[idx] = (__bf16)v;
        } else if (EPI == 3) {
          ((__bf16*)Cout)[idx] = (__bf16)v;
        } else {
          float sg = 1.f / (1.f + __expf(-v));
          ((__bf16*)Cout)[idx] = (__bf16)sg;
        }
      }
    }
  }
}

// ---------------------------------------------------------------------------
// WKV as a parallel log-sum-exp prefix sum. Vb is now bf16 (linear path;
// k stays f32 since it feeds exp()).
// ---------------------------------------------------------------------------
__global__ void wkv_part_kernel(const float* __restrict__ Kb,
                                const __bf16* __restrict__ Vb,
                                float* __restrict__ pM,
                                float* __restrict__ pA,
                                float* __restrict__ pB)
{
  const int gid = blockIdx.x * blockDim.x + threadIdx.x;
  const int d = gid & (DD - 1);
  const int rest = gid >> 11;
  const int c = rest & (WC - 1);
  const int b = rest >> 6;
  const float* kp  = Kb + ((size_t)b * TT + (size_t)c * WL) * DD + d;
  const __bf16* vp = Vb + ((size_t)b * TT + (size_t)c * WL) * DD + d;
  float M = -1e38f, A = 0.f, Bv = 0.f;
  for (int t = 0; t < WL; t++) {
    const float k = kp[(size_t)t * DD];
    const float v = (float)vp[(size_t)t * DD];
    const float q = fmaxf(M, k);
    const float s = __expf(M - q);
    const float e = __expf(k - q);
    A = A * s + e * v;
    Bv = Bv * s + e;
    M = q;
  }
  const size_t pi = ((size_t)b * WC + c) * DD + d;
  pM[pi] = M; pA[pi] = A; pB[pi] = Bv;
}

__global__ void wkv_scan_kernel(float* __restrict__ pM,
                                float* __restrict__ pA,
                                float* __restrict__ pB)
{
  const int gid = blockIdx.x * blockDim.x + threadIdx.x;
  const int d = gid & (DD - 1);
  const int b = gid >> 11;
  float M = -1e38f, A = 0.f, Bv = 0.f;
  for (int c = 0; c < WC; c++) {
    const size_t pi = ((size_t)b * WC + c) * DD + d;
    const float m = pM[pi], a = pA[pi], bb = pB[pi];
    pM[pi] = M; pA[pi] = A; pB[pi] = Bv;
    const float q = fmaxf(M, m);
    const float s0 = __expf(M - q);
    const float s1 = __expf(m - q);
    A = A * s0 + a * s1;
    Bv = Bv * s0 + bb * s1;
    M = q;
  }
}

__global__ void wkv_out_kernel(const float* __restrict__ Kb,
                               const __bf16* __restrict__ Vb,
                               const float* __restrict__ pM,
                               const float* __restrict__ pA,
                               const float* __restrict__ pB,
                               const float* __restrict__ tfirstF,
                               float* __restrict__ out)
{
  const int gid = blockIdx.x * blockDim.x + threadIdx.x;
  const int d = gid & (DD - 1);
  const int rest = gid >> 11;
  const int c = rest & (WC - 1);
  const int b = rest >> 6;
  const size_t pi = ((size_t)b * WC + c) * DD + d;
  float M = pM[pi], A = pA[pi], Bv = pB[pi];
  const float u = tfirstF[d];
  const size_t base = ((size_t)b * TT + (size_t)c * WL) * DD + d;
  const float* kp  = Kb + base;
  const __bf16* vp = Vb + base;
  float*       op  = out + base;
  for (int t = 0; t < WL; t++) {
    const float k = kp[(size_t)t * DD];
    const float v = (float)vp[(size_t)t * DD];
    const float ku = k + u;
    const float qo = fmaxf(M, ku);
    const float so = __expf(M - qo);
    const float eo = __expf(ku - qo);
    op[(size_t)t * DD] = __fdividef(A * so + v * eo, Bv * so + eo);
    const float q = fmaxf(M, k);
    const float s = __expf(M - q);
    const float e = __expf(k - q);
    A = A * s + e * v;
    Bv = Bv * s + e;
    M = q;
  }
}

// ---------------------------------------------------------------------------
// Kernel 4: LayerNorm over D + multiply by r -> rwkv (bf16) (unchanged)
// ---------------------------------------------------------------------------
__global__ void ln_kernel(const float* __restrict__ wkv,
                          const __bf16* __restrict__ rbuf,
                          const float* __restrict__ g,
                          const float* __restrict__ beta,
                          __bf16* __restrict__ out)
{
  const int row = blockIdx.x;
  const int tid = threadIdx.x;
  const float* xr = wkv + (size_t)row * DD;

  float vals[8];
  float s = 0.f, sq = 0.f;
  #pragma unroll
  for (int j = 0; j < 8; j++) {
    float v = xr[tid + j * 256];
    vals[j] = v;
    s += v;
    sq += v * v;
  }
  #pragma unroll
  for (int off = 1; off < 64; off <<= 1) {
    s  += __shfl_xor(s, off);
    sq += __shfl_xor(sq, off);
  }
  __shared__ float ls[4], lsq[4];
  const int wave = tid >> 6;
  if ((tid & 63) == 0) { ls[wave] = s; lsq[wave] = sq; }
  __syncthreads();
  s  = ls[0] + ls[1] + ls[2] + ls[3];
  sq = lsq[0] + lsq[1] + lsq[2] + lsq[3];

  const float mu = s * (1.f / DD);
  const float var = sq * (1.f / DD) - mu * mu;
  const float rs = rsqrtf(var + 1e-5f);

  #pragma unroll
  for (int j = 0; j < 8; j++) {
    const int dcol = tid + j * 256;
    const size_t idx = (size_t)row * DD + dcol;
    float v = (vals[j] - mu) * rs * g[dcol] + beta[dcol];
    float rr = (float)rbuf[idx];
    out[idx] = (__bf16)(rr * v);
  }
}

// ---------------------------------------------------------------------------
extern "C" void kernel_launch(void* const* d_in, const int* in_sizes, int n_in,
                              void* d_out, int out_size, void* d_ws, size_t ws_size,
                              hipStream_t stream) {
  const void* x      = d_in[0];
  const void* Wk     = d_in[1];
  const void* Wv     = d_in[2];
  const void* Wr     = d_in[3];
  const void* Wo     = d_in[4];
  const void* tmk    = d_in[5];
  const void* tmv    = d_in[6];
  const void* tmr    = d_in[7];
  const void* tdec   = d_in[8];
  const void* tfirst = d_in[9];
  const void* lng    = d_in[10];
  const void* lnb    = d_in[11];

  char* ws = (char*)d_ws;
  const size_t SZ_BF = (size_t)MM * DD * 2;   // 64 MiB
  const size_t SZ_F  = (size_t)MM * DD * 4;   // 128 MiB
  const size_t SZ_W  = (size_t)DD * DD * 2;   // 8 MiB
  __bf16* XK   = (__bf16*)(ws);
  __bf16* XV   = (__bf16*)(ws + SZ_BF);
  __bf16* XR   = (__bf16*)(ws + 2 * SZ_BF);
  float*  Kb   = (float*)(ws + 3 * SZ_BF);
  __bf16* Vb   = (__bf16*)(ws + 3 * SZ_BF + SZ_F);   // bf16 now (region reused)
  __bf16* WkB  = (__bf16*)(ws + 3 * SZ_BF + 2 * SZ_F);
  __bf16* WvB  = (__bf16*)(ws + 3 * SZ_BF + 2 * SZ_F + SZ_W);
  __bf16* WrB  = (__bf16*)(ws + 3 * SZ_BF + 2 * SZ_F + 2 * SZ_W);
  __bf16* WoB  = (__bf16*)(ws + 3 * SZ_BF + 2 * SZ_F + 3 * SZ_W);
  char*   smal = ws + 3 * SZ_BF + 2 * SZ_F + 4 * SZ_W;
  int*    flag    = (int*)smal;
  float*  tdecF   = (float*)(smal + 64);
  float*  tfirstF = tdecF + DD;
  float*  lngF    = tdecF + 2 * DD;
  float*  lnbF    = tdecF + 3 * DD;
  float*  tmkF    = tdecF + 4 * DD;
  float*  tmvF    = tdecF + 5 * DD;
  float*  tmrF    = tdecF + 6 * DD;
  float*  Wkv  = (float*)(ws);                 // over XK+XV (dead after GEMMs)
  __bf16* Rwkv = (__bf16*)(ws + 2 * SZ_BF);    // over XR
  __bf16* Rb   = (__bf16*)d_out;               // d_out as scratch until final GEMM
  float* pM = (float*)(ws + 2 * SZ_BF);
  float* pA = pM + (size_t)BB * WC * DD;
  float* pB = pA + (size_t)BB * WC * DD;

  detect_small_kernel<<<dim3(1), dim3(256), 0, stream>>>(
      tdec, tfirst, lng, lnb, tmk, tmv, tmr,
      flag, tdecF, tfirstF, lngF, lnbF, tmkF, tmvF, tmrF);

  convert_w_kernel<<<dim3(512), dim3(256), 0, stream>>>(Wk, WkB, flag);
  convert_w_kernel<<<dim3(512), dim3(256), 0, stream>>>(Wv, WvB, flag);
  convert_w_kernel<<<dim3(512), dim3(256), 0, stream>>>(Wr, WrB, flag);
  convert_w_kernel<<<dim3(512), dim3(256), 0, stream>>>(Wo, WoB, flag);

  mix_kernel<<<dim3(4096), dim3(256), 0, stream>>>(x, tmkF, tmvF, tmrF, flag, XK, XV, XR);

  // 256x256 tiles: 64*8 = 512 blocks, 1024 threads (16 waves)
  dim3 g(512), blk(1024);
  gemm_bt<0><<<g, blk, 0, stream>>>(XK, WkB, (void*)Kb, flag, MM, DD, DD);
  gemm_bt<3><<<g, blk, 0, stream>>>(XV, WvB, (void*)Vb, flag, MM, DD, DD);
  gemm_bt<2><<<g, blk, 0, stream>>>(XR, WrB, (void*)Rb, flag, MM, DD, DD);

  wkv_part_kernel<<<dim3((BB * DD * WC) / 256), dim3(256), 0, stream>>>(Kb, Vb, pM, pA, pB);
  wkv_scan_kernel<<<dim3((BB * DD) / 256), dim3(256), 0, stream>>>(pM, pA, pB);
  wkv_out_kernel<<<dim3((BB * DD * WC) / 256), dim3(256), 0, stream>>>(Kb, Vb, pM, pA, pB, tfirstF, Wkv);

  ln_kernel<<<dim3(MM), dim3(256), 0, stream>>>(Wkv, Rb, lngF, lnbF, Rwkv);

  gemm_bt<1><<<g, blk, 0, stream>>>(Rwkv, WoB, d_out, flag, MM, DD, DD);
}

// Round 8
// 906.024 us; speedup vs baseline: 1.5761x; 1.5761x over previous
//
#include <hip/hip_runtime.h>
#include <hip/hip_bf16.h>
#include <stdint.h>

// Problem constants
#define BB 4
#define TT 4096
#define DD 2048
#define MM (BB*TT)   // 16384 rows
#define WC 64        // wkv chunks per sequence
#define WL 64        // wkv chunk length (WC*WL == TT)

typedef __bf16 bf16x8 __attribute__((ext_vector_type(8)));
typedef float  f32x4  __attribute__((ext_vector_type(4)));

__device__ __forceinline__ void g2l16(const void* g, void* l) {
  __builtin_amdgcn_global_load_lds(
      (const __attribute__((address_space(1))) void*)g,
      (__attribute__((address_space(3))) void*)l,
      16, 0, 0);
}

// ---------------------------------------------------------------------------
// Kernel 0: dtype detect + convert small vectors to fp32.
// ---------------------------------------------------------------------------
__global__ void detect_small_kernel(const void* __restrict__ tdec_raw,
                                    const void* __restrict__ tfirst_raw,
                                    const void* __restrict__ lng_raw,
                                    const void* __restrict__ lnb_raw,
                                    const void* __restrict__ tmk_raw,
                                    const void* __restrict__ tmv_raw,
                                    const void* __restrict__ tmr_raw,
                                    int* __restrict__ flag,
                                    float* __restrict__ tdecF,
                                    float* __restrict__ tfirstF,
                                    float* __restrict__ lngF,
                                    float* __restrict__ lnbF,
                                    float* __restrict__ tmkF,
                                    float* __restrict__ tmvF,
                                    float* __restrict__ tmrF)
{
  const uint32_t w0 = *(const uint32_t*)tdec_raw;
  const int isf32 = ((w0 & 0xFFFFu) == 0u) ? 1 : 0;
  if (threadIdx.x == 0) *flag = isf32;
  for (int d = threadIdx.x; d < DD; d += blockDim.x) {
    if (isf32) {
      tdecF[d]   = ((const float*)tdec_raw)[d];
      tfirstF[d] = ((const float*)tfirst_raw)[d];
      lngF[d]    = ((const float*)lng_raw)[d];
      lnbF[d]    = ((const float*)lnb_raw)[d];
      tmkF[d]    = ((const float*)tmk_raw)[d];
      tmvF[d]    = ((const float*)tmv_raw)[d];
      tmrF[d]    = ((const float*)tmr_raw)[d];
    } else {
      tdecF[d]   = (float)((const __bf16*)tdec_raw)[d];
      tfirstF[d] = (float)((const __bf16*)tfirst_raw)[d];
      lngF[d]    = (float)((const __bf16*)lng_raw)[d];
      lnbF[d]    = (float)((const __bf16*)lnb_raw)[d];
      tmkF[d]    = (float)((const __bf16*)tmk_raw)[d];
      tmvF[d]    = (float)((const __bf16*)tmv_raw)[d];
      tmrF[d]    = (float)((const __bf16*)tmr_raw)[d];
    }
  }
}

// ---------------------------------------------------------------------------
// Kernel 0b: convert one DxD weight matrix to canonical bf16
// ---------------------------------------------------------------------------
__global__ void convert_w_kernel(const void* __restrict__ src,
                                 __bf16* __restrict__ dst,
                                 const int* __restrict__ flagp)
{
  const int isf32 = *flagp;
  const int64_t NV = (int64_t)DD * DD / 8;
  for (int64_t v = blockIdx.x * (int64_t)blockDim.x + threadIdx.x;
       v < NV; v += (int64_t)gridDim.x * blockDim.x) {
    const int64_t i = v * 8;
    bf16x8 o;
    if (isf32) {
      const float* sf = (const float*)src;
      f32x4 a = *(const f32x4*)(sf + i);
      f32x4 b = *(const f32x4*)(sf + i + 4);
      #pragma unroll
      for (int e = 0; e < 4; e++) { o[e] = (__bf16)a[e]; o[e+4] = (__bf16)b[e]; }
    } else {
      o = *(const bf16x8*)((const __bf16*)src + i);
    }
    *(bf16x8*)(dst + i) = o;
  }
}

// ---------------------------------------------------------------------------
// Kernel 1: token-shift mix -> xk, xv, xr (bf16)
// ---------------------------------------------------------------------------
__global__ void mix_kernel(const void* __restrict__ xraw,
                           const float* __restrict__ tmkF,
                           const float* __restrict__ tmvF,
                           const float* __restrict__ tmrF,
                           const int* __restrict__ flagp,
                           __bf16* __restrict__ xk,
                           __bf16* __restrict__ xv,
                           __bf16* __restrict__ xr)
{
  const int isf32 = *flagp;
  const int64_t NV = (int64_t)MM * DD / 8;
  for (int64_t v = blockIdx.x * (int64_t)blockDim.x + threadIdx.x;
       v < NV; v += (int64_t)gridDim.x * blockDim.x) {
    const int64_t i = v * 8;
    const int d = (int)(i & (DD - 1));
    const int64_t td = i & ((int64_t)TT * DD - 1);
    const bool has_prev = (td >= DD);
    float xc[8], xp[8];
    if (isf32) {
      const float* xf = (const float*)xraw;
      f32x4 a = *(const f32x4*)(xf + i);
      f32x4 b = *(const f32x4*)(xf + i + 4);
      #pragma unroll
      for (int e = 0; e < 4; e++) { xc[e] = a[e]; xc[e+4] = b[e]; }
      if (has_prev) {
        f32x4 c = *(const f32x4*)(xf + i - DD);
        f32x4 dd4 = *(const f32x4*)(xf + i - DD + 4);
        #pragma unroll
        for (int e = 0; e < 4; e++) { xp[e] = c[e]; xp[e+4] = dd4[e]; }
      } else {
        #pragma unroll
        for (int e = 0; e < 8; e++) xp[e] = 0.f;
      }
    } else {
      const __bf16* xb = (const __bf16*)xraw;
      bf16x8 a = *(const bf16x8*)(xb + i);
      #pragma unroll
      for (int e = 0; e < 8; e++) xc[e] = (float)a[e];
      if (has_prev) {
        bf16x8 c = *(const bf16x8*)(xb + i - DD);
        #pragma unroll
        for (int e = 0; e < 8; e++) xp[e] = (float)c[e];
      } else {
        #pragma unroll
        for (int e = 0; e < 8; e++) xp[e] = 0.f;
      }
    }
    bf16x8 ok, ov, orr;
    #pragma unroll
    for (int e = 0; e < 8; e++) {
      const float diff = xc[e] - xp[e];
      ok[e]  = (__bf16)(xp[e] + tmkF[d + e] * diff);
      ov[e]  = (__bf16)(xp[e] + tmvF[d + e] * diff);
      orr[e] = (__bf16)(xp[e] + tmrF[d + e] * diff);
    }
    *(bf16x8*)(xk + i) = ok;
    *(bf16x8*)(xv + i) = ov;
    *(bf16x8*)(xr + i) = orr;
  }
}

// ---------------------------------------------------------------------------
// Kernel 2: GEMM  C[m,n] = sum_k A[m,k] * Bm[n,k]   (B^T layout, bf16 MFMA)
//
// Round-8: r3's GEMM verbatim (best measured: 174us, 0 conflicts, no spill)
// with ONE change — the block->tile map. Evidence from r0-r7: every round
// obeys dur = hbm_bytes / ~2.35 TB/s (r0 2.29, r1 2.42, r2-spill 2.37,
// r3 2.37, r5 2.31, r7 2.45) -> the GEMM is traffic-bound, not stall-bound;
// all schedule work was optimizing a non-binding constraint. FETCH 292 MB vs
// 72 MB ideal: old map put colblk==XCD, so each XCD streamed ALL of A (64MB)
// through its private L2 -> 512 MB of A L2-fill.
//
// New map: xcd = bid&7 (HW round-robin), colblk = (bid>>3)&7,
// rowblk = xcd*8 + (bid>>6). The 8 blocks sharing an A panel (1 MB) are
// stride-8 in bid -> co-resident on the SAME XCD: A panel L2-fetched once,
// 7 hits. Resident window/XCD = 4 A panels = 4 MB = L2 size. B (8 MB total)
// is L3-trivial. Logical A fill: 512 -> 64 MB.
//
// Schedule (r3, unchanged): per tile t (CB = buf[t&1], OB = other):
//   RD a0,b0,b1 (16 ds_reads); stage (t+1).A -> OB; Q1,Q2;
//   sched_barrier; RD a1; lgkmcnt(8); barrier;
//   stage (t+2).B -> CB; Q3,Q4; vmcnt(4); barrier.
// Invariant: entering tile t, buf[t&1] resident, (t+1).B (4 loads)
// outstanding; never vmcnt(0) in loop. Swizzle: chunk c of row r at c^(r&7),
// both-sides (conflicts==0 measured).
// EPI: 0 = f32 store, 1 = final (flag ? f32 : bf16), 2 = sigmoid->bf16,
//      3 = bf16 store (V path; proven absmax-neutral in r7).
// ---------------------------------------------------------------------------
#define BARX()   __builtin_amdgcn_s_barrier()
#define SCHEDB() __builtin_amdgcn_sched_barrier(0)
#define WAITL(n) asm volatile("s_waitcnt lgkmcnt(" #n ")" ::: "memory")
#define WAITV(n) asm volatile("s_waitcnt vmcnt(" #n ")" ::: "memory")

#define STAGE_AH_AT(PB, h, kt) do { \
    g2l16(Asrc + (size_t)((h)*128     ) * Kd + (size_t)(kt)*64, smem + (PB) + ((h)*128     )*64 + tid*8); \
    g2l16(Asrc + (size_t)((h)*128 + 64) * Kd + (size_t)(kt)*64, smem + (PB) + ((h)*128 + 64)*64 + tid*8); \
  } while (0)
#define STAGE_BH_AT(PB, h, kt) do { \
    g2l16(Bsrc + (size_t)((h)*128     ) * Kd + (size_t)(kt)*64, smem + 16384 + (PB) + ((h)*128     )*64 + tid*8); \
    g2l16(Bsrc + (size_t)((h)*128 + 64) * Kd + (size_t)(kt)*64, smem + 16384 + (PB) + ((h)*128 + 64)*64 + tid*8); \
  } while (0)

#define RD_A0(pb) do { _Pragma("unroll") for (int i_ = 0; i_ < 4; i_++) { \
    a0[i_][0] = *(const bf16x8*)(smem + (pb) + (aoff0 + i_*1024)); \
    a0[i_][1] = *(const bf16x8*)(smem + (pb) + ((aoff0 + i_*1024) ^ 32)); } } while (0)
#define RD_A1(pb) do { _Pragma("unroll") for (int i_ = 0; i_ < 4; i_++) { \
    a1[i_][0] = *(const bf16x8*)(smem + (pb) + (aoff0 + (i_+4)*1024)); \
    a1[i_][1] = *(const bf16x8*)(smem + (pb) + ((aoff0 + (i_+4)*1024) ^ 32)); } } while (0)
#define RD_B0(pb) do { _Pragma("unroll") for (int j_ = 0; j_ < 2; j_++) { \
    b0[j_][0] = *(const bf16x8*)(smem + (pb) + (boff0 + j_*1024)); \
    b0[j_][1] = *(const bf16x8*)(smem + (pb) + ((boff0 + j_*1024) ^ 32)); } } while (0)
#define RD_B1(pb) do { _Pragma("unroll") for (int j_ = 0; j_ < 2; j_++) { \
    b1[j_][0] = *(const bf16x8*)(smem + (pb) + (boff0 + (j_+2)*1024)); \
    b1[j_][1] = *(const bf16x8*)(smem + (pb) + ((boff0 + (j_+2)*1024) ^ 32)); } } while (0)

#define MFMA16(af, bf, IO, JO) do { \
    _Pragma("unroll") for (int i_ = 0; i_ < 4; i_++) { \
    _Pragma("unroll") for (int j_ = 0; j_ < 2; j_++) { \
      acc[(IO)+i_][(JO)+j_] = __builtin_amdgcn_mfma_f32_16x16x32_bf16((af)[i_][0], (bf)[j_][0], acc[(IO)+i_][(JO)+j_], 0, 0, 0); \
      acc[(IO)+i_][(JO)+j_] = __builtin_amdgcn_mfma_f32_16x16x32_bf16((af)[i_][1], (bf)[j_][1], acc[(IO)+i_][(JO)+j_], 0, 0, 0); \
    } } } while (0)

#define TILE_BODY(CB, OB, tA, tB) do { \
    RD_A0(CB); RD_B0(CB); RD_B1(CB); \
    STAGE_AH_AT(OB, 0, tA); STAGE_AH_AT(OB, 1, tA); \
    __builtin_amdgcn_s_setprio(1); \
    MFMA16(a0, b0, 0, 0); \
    MFMA16(a0, b1, 0, 2); \
    __builtin_amdgcn_s_setprio(0); \
    SCHEDB(); \
    RD_A1(CB); \
    WAITL(8); \
    BARX(); \
    SCHEDB(); \
    STAGE_BH_AT(CB, 0, tB); STAGE_BH_AT(CB, 1, tB); \
    __builtin_amdgcn_s_setprio(1); \
    MFMA16(a1, b1, 4, 2); \
    MFMA16(a1, b0, 4, 0); \
    __builtin_amdgcn_s_setprio(0); \
    WAITV(4); \
    BARX(); \
    SCHEDB(); \
  } while (0)

template <int EPI>
__global__ void __launch_bounds__(512, 2)
gemm_bt(const __bf16* __restrict__ A,
        const __bf16* __restrict__ Bm,
        void* __restrict__ Cout,
        const int* __restrict__ flagp,
        int Md, int Nd, int Kd)
{
  __shared__ __bf16 smem[65536];   // 128 KiB
  const int isf32 = (EPI == 1) ? *flagp : 0;
  const int tid  = threadIdx.x;    // 0..511
  const int lane = tid & 63;
  const int wv   = tid >> 6;       // 0..7
  const int wm   = wv >> 2;        // wave row 0..1 (128 rows each)
  const int wn   = wv & 3;         // wave col 0..3 (64 cols each)
  const int l16  = lane & 15;
  const int qd   = lane >> 4;

  // A-reuse XCD map: the 8 colblk-blocks of one rowblk are stride-8 in bid
  // -> same XCD -> A panel fetched into that XCD's L2 once. Resident window
  // per XCD = 4 A panels = 4 MB = L2 size.
  const int bid    = blockIdx.x;          // 0..511
  const int xcd    = bid & 7;
  const int colblk = (bid >> 3) & 7;
  const int rowsub = bid >> 6;            // 0..7
  const int row0   = (xcd * 8 + rowsub) * 256;
  const int col0   = colblk * 256;

  // staging: wave wv stages rows wv*8+(lane>>3), chunk (lane&7)^(lane>>3)
  // (inverse swizzle on the global source; LDS dest stays linear).
  const int srow   = (wv << 3) + (lane >> 3);
  const int schunk = (lane & 7) ^ (lane >> 3);
  const __bf16* Asrc = A  + (size_t)(row0 + srow) * Kd + schunk * 8;
  const __bf16* Bsrc = Bm + (size_t)(col0 + srow) * Kd + schunk * 8;

  // ds_read bases (buf-relative elem offsets), chunk swizzled by row&7 = l16&7
  const int c0    = (qd ^ (l16 & 7)) * 8;
  const int aoff0 = (wm * 128 + l16) * 64 + c0;           // i=0, kk=0
  const int boff0 = 16384 + (wn * 64 + l16) * 64 + c0;    // j=0, kk=0

  f32x4 acc[8][4];
  #pragma unroll
  for (int i = 0; i < 8; i++)
    #pragma unroll
    for (int j = 0; j < 4; j++)
      acc[i][j] = (f32x4){0.f, 0.f, 0.f, 0.f};

  bf16x8 a0[4][2], a1[4][2], b0[2][2], b1[2][2];

  // Prologue: tile0 A+B -> buf0, tile1 B -> buf1; vmcnt(4) leaves tile1.B
  // in flight (steady-state invariant).
  STAGE_AH_AT(0, 0, 0); STAGE_AH_AT(0, 1, 0);
  STAGE_BH_AT(0, 0, 0); STAGE_BH_AT(0, 1, 0);
  STAGE_BH_AT(32768, 0, 1); STAGE_BH_AT(32768, 1, 1);
  WAITV(4);
  BARX();
  SCHEDB();

  const int ntile = Kd >> 6;       // 32
  #pragma unroll 1
  for (int it = 0; it < (ntile - 2) / 2; ++it) {   // tiles 0..ntile-3
    const int t = it << 1;
    TILE_BODY(0,     32768, t + 1, t + 2);
    TILE_BODY(32768, 0,     t + 2, t + 3);
  }

  // tile ntile-2 (buf0): stage only (ntile-1).A; full vm drain at the end.
  {
    RD_A0(0); RD_B0(0); RD_B1(0);
    STAGE_AH_AT(32768, 0, ntile - 1); STAGE_AH_AT(32768, 1, ntile - 1);
    __builtin_amdgcn_s_setprio(1);
    MFMA16(a0, b0, 0, 0);
    MFMA16(a0, b1, 0, 2);
    __builtin_amdgcn_s_setprio(0);
    SCHEDB();
    RD_A1(0);
    __builtin_amdgcn_s_setprio(1);
    MFMA16(a1, b1, 4, 2);
    MFMA16(a1, b0, 4, 0);
    __builtin_amdgcn_s_setprio(0);
    WAITV(0);
    BARX();
    SCHEDB();
  }
  // tile ntile-1 (buf1): no staging, no barriers.
  {
    RD_A0(32768); RD_B0(32768); RD_B1(32768);
    __builtin_amdgcn_s_setprio(1);
    MFMA16(a0, b0, 0, 0);
    MFMA16(a0, b1, 0, 2);
    __builtin_amdgcn_s_setprio(0);
    SCHEDB();
    RD_A1(32768);
    __builtin_amdgcn_s_setprio(1);
    MFMA16(a1, b1, 4, 2);
    MFMA16(a1, b0, 4, 0);
    __builtin_amdgcn_s_setprio(0);
  }

  // epilogue: C/D layout col=lane&15, row=quad*4+reg (verified m89/m91)
  #pragma unroll
  for (int i = 0; i < 8; i++) {
    const int rb = row0 + wm * 128 + i * 16 + qd * 4;
    #pragma unroll
    for (int j = 0; j < 4; j++) {
      const int c = col0 + wn * 64 + j * 16 + l16;
      #pragma unroll
      for (int reg = 0; reg < 4; reg++) {
        const size_t idx = (size_t)(rb + reg) * Nd + c;
        float v = acc[i][j][reg];
        if (EPI == 0) {
          ((float*)Cout)[idx] = v;
        } else if (EPI == 1) {
          if (isf32) ((float*)Cout)[idx] = v;
          else       ((__bf16*)Cout)[idx] = (__bf16)v;
        } else if (EPI == 3) {
          ((__bf16*)Cout)[idx] = (__bf16)v;
        } else {
          float s = 1.f / (1.f + __expf(-v));
          ((__bf16*)Cout)[idx] = (__bf16)s;
        }
      }
    }
  }
}

// ---------------------------------------------------------------------------
// WKV as a parallel log-sum-exp prefix sum. Vb is bf16 (linear path; proven
// absmax-neutral in r7). k stays f32 (feeds exp()).
// ---------------------------------------------------------------------------
__global__ void wkv_part_kernel(const float* __restrict__ Kb,
                                const __bf16* __restrict__ Vb,
                                float* __restrict__ pM,
                                float* __restrict__ pA,
                                float* __restrict__ pB)
{
  const int gid = blockIdx.x * blockDim.x + threadIdx.x;
  const int d = gid & (DD - 1);
  const int rest = gid >> 11;
  const int c = rest & (WC - 1);
  const int b = rest >> 6;
  const float* kp  = Kb + ((size_t)b * TT + (size_t)c * WL) * DD + d;
  const __bf16* vp = Vb + ((size_t)b * TT + (size_t)c * WL) * DD + d;
  float M = -1e38f, A = 0.f, Bv = 0.f;
  for (int t = 0; t < WL; t++) {
    const float k = kp[(size_t)t * DD];
    const float v = (float)vp[(size_t)t * DD];
    const float q = fmaxf(M, k);
    const float s = __expf(M - q);
    const float e = __expf(k - q);
    A = A * s + e * v;
    Bv = Bv * s + e;
    M = q;
  }
  const size_t pi = ((size_t)b * WC + c) * DD + d;
  pM[pi] = M; pA[pi] = A; pB[pi] = Bv;
}

__global__ void wkv_scan_kernel(float* __restrict__ pM,
                                float* __restrict__ pA,
                                float* __restrict__ pB)
{
  const int gid = blockIdx.x * blockDim.x + threadIdx.x;
  const int d = gid & (DD - 1);
  const int b = gid >> 11;
  float M = -1e38f, A = 0.f, Bv = 0.f;
  for (int c = 0; c < WC; c++) {
    const size_t pi = ((size_t)b * WC + c) * DD + d;
    const float m = pM[pi], a = pA[pi], bb = pB[pi];
    pM[pi] = M; pA[pi] = A; pB[pi] = Bv;
    const float q = fmaxf(M, m);
    const float s0 = __expf(M - q);
    const float s1 = __expf(m - q);
    A = A * s0 + a * s1;
    Bv = Bv * s0 + bb * s1;
    M = q;
  }
}

__global__ void wkv_out_kernel(const float* __restrict__ Kb,
                               const __bf16* __restrict__ Vb,
                               const float* __restrict__ pM,
                               const float* __restrict__ pA,
                               const float* __restrict__ pB,
                               const float* __restrict__ tfirstF,
                               float* __restrict__ out)
{
  const int gid = blockIdx.x * blockDim.x + threadIdx.x;
  const int d = gid & (DD - 1);
  const int rest = gid >> 11;
  const int c = rest & (WC - 1);
  const int b = rest >> 6;
  const size_t pi = ((size_t)b * WC + c) * DD + d;
  float M = pM[pi], A = pA[pi], Bv = pB[pi];
  const float u = tfirstF[d];
  const size_t base = ((size_t)b * TT + (size_t)c * WL) * DD + d;
  const float* kp  = Kb + base;
  const __bf16* vp = Vb + base;
  float*       op  = out + base;
  for (int t = 0; t < WL; t++) {
    const float k = kp[(size_t)t * DD];
    const float v = (float)vp[(size_t)t * DD];
    const float ku = k + u;
    const float qo = fmaxf(M, ku);
    const float so = __expf(M - qo);
    const float eo = __expf(ku - qo);
    op[(size_t)t * DD] = __fdividef(A * so + v * eo, Bv * so + eo);
    const float q = fmaxf(M, k);
    const float s = __expf(M - q);
    const float e = __expf(k - q);
    A = A * s + e * v;
    Bv = Bv * s + e;
    M = q;
  }
}

// ---------------------------------------------------------------------------
// Kernel 4: LayerNorm over D + multiply by r -> rwkv (bf16) (unchanged)
// ---------------------------------------------------------------------------
__global__ void ln_kernel(const float* __restrict__ wkv,
                          const __bf16* __restrict__ rbuf,
                          const float* __restrict__ g,
                          const float* __restrict__ beta,
                          __bf16* __restrict__ out)
{
  const int row = blockIdx.x;
  const int tid = threadIdx.x;
  const float* xr = wkv + (size_t)row * DD;

  float vals[8];
  float s = 0.f, sq = 0.f;
  #pragma unroll
  for (int j = 0; j < 8; j++) {
    float v = xr[tid + j * 256];
    vals[j] = v;
    s += v;
    sq += v * v;
  }
  #pragma unroll
  for (int off = 1; off < 64; off <<= 1) {
    s  += __shfl_xor(s, off);
    sq += __shfl_xor(sq, off);
  }
  __shared__ float ls[4], lsq[4];
  const int wave = tid >> 6;
  if ((tid & 63) == 0) { ls[wave] = s; lsq[wave] = sq; }
  __syncthreads();
  s  = ls[0] + ls[1] + ls[2] + ls[3];
  sq = lsq[0] + lsq[1] + lsq[2] + lsq[3];

  const float mu = s * (1.f / DD);
  const float var = sq * (1.f / DD) - mu * mu;
  const float rs = rsqrtf(var + 1e-5f);

  #pragma unroll
  for (int j = 0; j < 8; j++) {
    const int dcol = tid + j * 256;
    const size_t idx = (size_t)row * DD + dcol;
    float v = (vals[j] - mu) * rs * g[dcol] + beta[dcol];
    float rr = (float)rbuf[idx];
    out[idx] = (__bf16)(rr * v);
  }
}

// ---------------------------------------------------------------------------
extern "C" void kernel_launch(void* const* d_in, const int* in_sizes, int n_in,
                              void* d_out, int out_size, void* d_ws, size_t ws_size,
                              hipStream_t stream) {
  const void* x      = d_in[0];
  const void* Wk     = d_in[1];
  const void* Wv     = d_in[2];
  const void* Wr     = d_in[3];
  const void* Wo     = d_in[4];
  const void* tmk    = d_in[5];
  const void* tmv    = d_in[6];
  const void* tmr    = d_in[7];
  const void* tdec   = d_in[8];
  const void* tfirst = d_in[9];
  const void* lng    = d_in[10];
  const void* lnb    = d_in[11];

  char* ws = (char*)d_ws;
  const size_t SZ_BF = (size_t)MM * DD * 2;   // 64 MiB
  const size_t SZ_F  = (size_t)MM * DD * 4;   // 128 MiB
  const size_t SZ_W  = (size_t)DD * DD * 2;   // 8 MiB
  __bf16* XK   = (__bf16*)(ws);
  __bf16* XV   = (__bf16*)(ws + SZ_BF);
  __bf16* XR   = (__bf16*)(ws + 2 * SZ_BF);
  float*  Kb   = (float*)(ws + 3 * SZ_BF);
  __bf16* Vb   = (__bf16*)(ws + 3 * SZ_BF + SZ_F);   // bf16 (region reused)
  __bf16* WkB  = (__bf16*)(ws + 3 * SZ_BF + 2 * SZ_F);
  __bf16* WvB  = (__bf16*)(ws + 3 * SZ_BF + 2 * SZ_F + SZ_W);
  __bf16* WrB  = (__bf16*)(ws + 3 * SZ_BF + 2 * SZ_F + 2 * SZ_W);
  __bf16* WoB  = (__bf16*)(ws + 3 * SZ_BF + 2 * SZ_F + 3 * SZ_W);
  char*   smal = ws + 3 * SZ_BF + 2 * SZ_F + 4 * SZ_W;
  int*    flag    = (int*)smal;
  float*  tdecF   = (float*)(smal + 64);
  float*  tfirstF = tdecF + DD;
  float*  lngF    = tdecF + 2 * DD;
  float*  lnbF    = tdecF + 3 * DD;
  float*  tmkF    = tdecF + 4 * DD;
  float*  tmvF    = tdecF + 5 * DD;
  float*  tmrF    = tdecF + 6 * DD;
  float*  Wkv  = (float*)(ws);                 // over XK+XV (dead after GEMMs)
  __bf16* Rwkv = (__bf16*)(ws + 2 * SZ_BF);    // over XR
  __bf16* Rb   = (__bf16*)d_out;               // d_out as scratch until final GEMM
  float* pM = (float*)(ws + 2 * SZ_BF);
  float* pA = pM + (size_t)BB * WC * DD;
  float* pB = pA + (size_t)BB * WC * DD;

  detect_small_kernel<<<dim3(1), dim3(256), 0, stream>>>(
      tdec, tfirst, lng, lnb, tmk, tmv, tmr,
      flag, tdecF, tfirstF, lngF, lnbF, tmkF, tmvF, tmrF);

  convert_w_kernel<<<dim3(512), dim3(256), 0, stream>>>(Wk, WkB, flag);
  convert_w_kernel<<<dim3(512), dim3(256), 0, stream>>>(Wv, WvB, flag);
  convert_w_kernel<<<dim3(512), dim3(256), 0, stream>>>(Wr, WrB, flag);
  convert_w_kernel<<<dim3(512), dim3(256), 0, stream>>>(Wo, WoB, flag);

  mix_kernel<<<dim3(4096), dim3(256), 0, stream>>>(x, tmkF, tmvF, tmrF, flag, XK, XV, XR);

  dim3 g(512), blk(512);   // 256x256 tiles; A-reuse XCD map inside kernel
  gemm_bt<0><<<g, blk, 0, stream>>>(XK, WkB, (void*)Kb, flag, MM, DD, DD);
  gemm_bt<3><<<g, blk, 0, stream>>>(XV, WvB, (void*)Vb, flag, MM, DD, DD);
  gemm_bt<2><<<g, blk, 0, stream>>>(XR, WrB, (void*)Rb, flag, MM, DD, DD);

  wkv_part_kernel<<<dim3((BB * DD * WC) / 256), dim3(256), 0, stream>>>(Kb, Vb, pM, pA, pB);
  wkv_scan_kernel<<<dim3((BB * DD) / 256), dim3(256), 0, stream>>>(pM, pA, pB);
  wkv_out_kernel<<<dim3((BB * DD * WC) / 256), dim3(256), 0, stream>>>(Kb, Vb, pM, pA, pB, tfirstF, Wkv);

  ln_kernel<<<dim3(MM), dim3(256), 0, stream>>>(Wkv, Rb, lngF, lnbF, Rwkv);

  gemm_bt<1><<<g, blk, 0, stream>>>(Rwkv, WoB, d_out, flag, MM, DD, DD);
}

// Round 9
// 897.737 us; speedup vs baseline: 1.5906x; 1.0092x over previous
//
#include <hip/hip_runtime.h>
#include <hip/hip_bf16.h>
#include <stdint.h>

// Problem constants
#define BB 4
#define TT 4096
#define DD 2048
#define MM (BB*TT)   // 16384 rows
#define WC 64        // wkv chunks per sequence
#define WL 64        // wkv chunk length (WC*WL == TT)

typedef __bf16 bf16x8 __attribute__((ext_vector_type(8)));
typedef __bf16 bf16x2 __attribute__((ext_vector_type(2)));
typedef float  f32x4  __attribute__((ext_vector_type(4)));

__device__ __forceinline__ void g2l16(const void* g, void* l) {
  __builtin_amdgcn_global_load_lds(
      (const __attribute__((address_space(1))) void*)g,
      (__attribute__((address_space(3))) void*)l,
      16, 0, 0);
}

// ---------------------------------------------------------------------------
// Kernel 0: dtype detect + convert small vectors to fp32.
// ---------------------------------------------------------------------------
__global__ void detect_small_kernel(const void* __restrict__ tdec_raw,
                                    const void* __restrict__ tfirst_raw,
                                    const void* __restrict__ lng_raw,
                                    const void* __restrict__ lnb_raw,
                                    const void* __restrict__ tmk_raw,
                                    const void* __restrict__ tmv_raw,
                                    const void* __restrict__ tmr_raw,
                                    int* __restrict__ flag,
                                    float* __restrict__ tdecF,
                                    float* __restrict__ tfirstF,
                                    float* __restrict__ lngF,
                                    float* __restrict__ lnbF,
                                    float* __restrict__ tmkF,
                                    float* __restrict__ tmvF,
                                    float* __restrict__ tmrF)
{
  const uint32_t w0 = *(const uint32_t*)tdec_raw;
  const int isf32 = ((w0 & 0xFFFFu) == 0u) ? 1 : 0;
  if (threadIdx.x == 0) *flag = isf32;
  for (int d = threadIdx.x; d < DD; d += blockDim.x) {
    if (isf32) {
      tdecF[d]   = ((const float*)tdec_raw)[d];
      tfirstF[d] = ((const float*)tfirst_raw)[d];
      lngF[d]    = ((const float*)lng_raw)[d];
      lnbF[d]    = ((const float*)lnb_raw)[d];
      tmkF[d]    = ((const float*)tmk_raw)[d];
      tmvF[d]    = ((const float*)tmv_raw)[d];
      tmrF[d]    = ((const float*)tmr_raw)[d];
    } else {
      tdecF[d]   = (float)((const __bf16*)tdec_raw)[d];
      tfirstF[d] = (float)((const __bf16*)tfirst_raw)[d];
      lngF[d]    = (float)((const __bf16*)lng_raw)[d];
      lnbF[d]    = (float)((const __bf16*)lnb_raw)[d];
      tmkF[d]    = (float)((const __bf16*)tmk_raw)[d];
      tmvF[d]    = (float)((const __bf16*)tmv_raw)[d];
      tmrF[d]    = (float)((const __bf16*)tmr_raw)[d];
    }
  }
}

// ---------------------------------------------------------------------------
// Kernel 0b: convert one DxD weight matrix to canonical bf16
// ---------------------------------------------------------------------------
__global__ void convert_w_kernel(const void* __restrict__ src,
                                 __bf16* __restrict__ dst,
                                 const int* __restrict__ flagp)
{
  const int isf32 = *flagp;
  const int64_t NV = (int64_t)DD * DD / 8;
  for (int64_t v = blockIdx.x * (int64_t)blockDim.x + threadIdx.x;
       v < NV; v += (int64_t)gridDim.x * blockDim.x) {
    const int64_t i = v * 8;
    bf16x8 o;
    if (isf32) {
      const float* sf = (const float*)src;
      f32x4 a = *(const f32x4*)(sf + i);
      f32x4 b = *(const f32x4*)(sf + i + 4);
      #pragma unroll
      for (int e = 0; e < 4; e++) { o[e] = (__bf16)a[e]; o[e+4] = (__bf16)b[e]; }
    } else {
      o = *(const bf16x8*)((const __bf16*)src + i);
    }
    *(bf16x8*)(dst + i) = o;
  }
}

// ---------------------------------------------------------------------------
// Kernel 1: token-shift mix -> xk, xv, xr (bf16)
// ---------------------------------------------------------------------------
__global__ void mix_kernel(const void* __restrict__ xraw,
                           const float* __restrict__ tmkF,
                           const float* __restrict__ tmvF,
                           const float* __restrict__ tmrF,
                           const int* __restrict__ flagp,
                           __bf16* __restrict__ xk,
                           __bf16* __restrict__ xv,
                           __bf16* __restrict__ xr)
{
  const int isf32 = *flagp;
  const int64_t NV = (int64_t)MM * DD / 8;
  for (int64_t v = blockIdx.x * (int64_t)blockDim.x + threadIdx.x;
       v < NV; v += (int64_t)gridDim.x * blockDim.x) {
    const int64_t i = v * 8;
    const int d = (int)(i & (DD - 1));
    const int64_t td = i & ((int64_t)TT * DD - 1);
    const bool has_prev = (td >= DD);
    float xc[8], xp[8];
    if (isf32) {
      const float* xf = (const float*)xraw;
      f32x4 a = *(const f32x4*)(xf + i);
      f32x4 b = *(const f32x4*)(xf + i + 4);
      #pragma unroll
      for (int e = 0; e < 4; e++) { xc[e] = a[e]; xc[e+4] = b[e]; }
      if (has_prev) {
        f32x4 c = *(const f32x4*)(xf + i - DD);
        f32x4 dd4 = *(const f32x4*)(xf + i - DD + 4);
        #pragma unroll
        for (int e = 0; e < 4; e++) { xp[e] = c[e]; xp[e+4] = dd4[e]; }
      } else {
        #pragma unroll
        for (int e = 0; e < 8; e++) xp[e] = 0.f;
      }
    } else {
      const __bf16* xb = (const __bf16*)xraw;
      bf16x8 a = *(const bf16x8*)(xb + i);
      #pragma unroll
      for (int e = 0; e < 8; e++) xc[e] = (float)a[e];
      if (has_prev) {
        bf16x8 c = *(const bf16x8*)(xb + i - DD);
        #pragma unroll
        for (int e = 0; e < 8; e++) xp[e] = (float)c[e];
      } else {
        #pragma unroll
        for (int e = 0; e < 8; e++) xp[e] = 0.f;
      }
    }
    bf16x8 ok, ov, orr;
    #pragma unroll
    for (int e = 0; e < 8; e++) {
      const float diff = xc[e] - xp[e];
      ok[e]  = (__bf16)(xp[e] + tmkF[d + e] * diff);
      ov[e]  = (__bf16)(xp[e] + tmvF[d + e] * diff);
      orr[e] = (__bf16)(xp[e] + tmrF[d + e] * diff);
    }
    *(bf16x8*)(xk + i) = ok;
    *(bf16x8*)(xv + i) = ov;
    *(bf16x8*)(xr + i) = orr;
  }
}

// ---------------------------------------------------------------------------
// Kernel 2: GEMM (r8 verbatim — session plateau at ~800 TF; 5 schedules,
// conflict-free LDS, counted vmcnt, A-reuse XCD map all equivalent. FETCH
// halved in r8 with dur unchanged -> not traffic-bound; dead time is
// barrier/wait convoy that schedule surgery doesn't move.)
//
// 256x256 tile, BK=64, 8 waves, derived-waits (2 barriers/tile), both-sides
// swizzle (0 conflicts), A-reuse XCD map (FETCH 292->119 MB measured).
// EPI: 0 = f32 store, 1 = final (flag ? f32 : bf16), 2 = sigmoid->bf16,
//      3 = bf16 store.
// ---------------------------------------------------------------------------
#define BARX()   __builtin_amdgcn_s_barrier()
#define SCHEDB() __builtin_amdgcn_sched_barrier(0)
#define WAITL(n) asm volatile("s_waitcnt lgkmcnt(" #n ")" ::: "memory")
#define WAITV(n) asm volatile("s_waitcnt vmcnt(" #n ")" ::: "memory")

#define STAGE_AH_AT(PB, h, kt) do { \
    g2l16(Asrc + (size_t)((h)*128     ) * Kd + (size_t)(kt)*64, smem + (PB) + ((h)*128     )*64 + tid*8); \
    g2l16(Asrc + (size_t)((h)*128 + 64) * Kd + (size_t)(kt)*64, smem + (PB) + ((h)*128 + 64)*64 + tid*8); \
  } while (0)
#define STAGE_BH_AT(PB, h, kt) do { \
    g2l16(Bsrc + (size_t)((h)*128     ) * Kd + (size_t)(kt)*64, smem + 16384 + (PB) + ((h)*128     )*64 + tid*8); \
    g2l16(Bsrc + (size_t)((h)*128 + 64) * Kd + (size_t)(kt)*64, smem + 16384 + (PB) + ((h)*128 + 64)*64 + tid*8); \
  } while (0)

#define RD_A0(pb) do { _Pragma("unroll") for (int i_ = 0; i_ < 4; i_++) { \
    a0[i_][0] = *(const bf16x8*)(smem + (pb) + (aoff0 + i_*1024)); \
    a0[i_][1] = *(const bf16x8*)(smem + (pb) + ((aoff0 + i_*1024) ^ 32)); } } while (0)
#define RD_A1(pb) do { _Pragma("unroll") for (int i_ = 0; i_ < 4; i_++) { \
    a1[i_][0] = *(const bf16x8*)(smem + (pb) + (aoff0 + (i_+4)*1024)); \
    a1[i_][1] = *(const bf16x8*)(smem + (pb) + ((aoff0 + (i_+4)*1024) ^ 32)); } } while (0)
#define RD_B0(pb) do { _Pragma("unroll") for (int j_ = 0; j_ < 2; j_++) { \
    b0[j_][0] = *(const bf16x8*)(smem + (pb) + (boff0 + j_*1024)); \
    b0[j_][1] = *(const bf16x8*)(smem + (pb) + ((boff0 + j_*1024) ^ 32)); } } while (0)
#define RD_B1(pb) do { _Pragma("unroll") for (int j_ = 0; j_ < 2; j_++) { \
    b1[j_][0] = *(const bf16x8*)(smem + (pb) + (boff0 + (j_+2)*1024)); \
    b1[j_][1] = *(const bf16x8*)(smem + (pb) + ((boff0 + (j_+2)*1024) ^ 32)); } } while (0)

#define MFMA16(af, bf, IO, JO) do { \
    _Pragma("unroll") for (int i_ = 0; i_ < 4; i_++) { \
    _Pragma("unroll") for (int j_ = 0; j_ < 2; j_++) { \
      acc[(IO)+i_][(JO)+j_] = __builtin_amdgcn_mfma_f32_16x16x32_bf16((af)[i_][0], (bf)[j_][0], acc[(IO)+i_][(JO)+j_], 0, 0, 0); \
      acc[(IO)+i_][(JO)+j_] = __builtin_amdgcn_mfma_f32_16x16x32_bf16((af)[i_][1], (bf)[j_][1], acc[(IO)+i_][(JO)+j_], 0, 0, 0); \
    } } } while (0)

#define TILE_BODY(CB, OB, tA, tB) do { \
    RD_A0(CB); RD_B0(CB); RD_B1(CB); \
    STAGE_AH_AT(OB, 0, tA); STAGE_AH_AT(OB, 1, tA); \
    __builtin_amdgcn_s_setprio(1); \
    MFMA16(a0, b0, 0, 0); \
    MFMA16(a0, b1, 0, 2); \
    __builtin_amdgcn_s_setprio(0); \
    SCHEDB(); \
    RD_A1(CB); \
    WAITL(8); \
    BARX(); \
    SCHEDB(); \
    STAGE_BH_AT(CB, 0, tB); STAGE_BH_AT(CB, 1, tB); \
    __builtin_amdgcn_s_setprio(1); \
    MFMA16(a1, b1, 4, 2); \
    MFMA16(a1, b0, 4, 0); \
    __builtin_amdgcn_s_setprio(0); \
    WAITV(4); \
    BARX(); \
    SCHEDB(); \
  } while (0)

template <int EPI>
__global__ void __launch_bounds__(512, 2)
gemm_bt(const __bf16* __restrict__ A,
        const __bf16* __restrict__ Bm,
        void* __restrict__ Cout,
        const int* __restrict__ flagp,
        int Md, int Nd, int Kd)
{
  __shared__ __bf16 smem[65536];   // 128 KiB
  const int isf32 = (EPI == 1) ? *flagp : 0;
  const int tid  = threadIdx.x;    // 0..511
  const int lane = tid & 63;
  const int wv   = tid >> 6;       // 0..7
  const int wm   = wv >> 2;        // wave row 0..1 (128 rows each)
  const int wn   = wv & 3;         // wave col 0..3 (64 cols each)
  const int l16  = lane & 15;
  const int qd   = lane >> 4;

  // A-reuse XCD map: the 8 colblk-blocks of one rowblk are stride-8 in bid
  // -> same XCD -> A panel fetched into that XCD's L2 once (FETCH 292->119MB
  // measured r8).
  const int bid    = blockIdx.x;          // 0..511
  const int xcd    = bid & 7;
  const int colblk = (bid >> 3) & 7;
  const int rowsub = bid >> 6;            // 0..7
  const int row0   = (xcd * 8 + rowsub) * 256;
  const int col0   = colblk * 256;

  // staging: wave wv stages rows wv*8+(lane>>3), chunk (lane&7)^(lane>>3)
  const int srow   = (wv << 3) + (lane >> 3);
  const int schunk = (lane & 7) ^ (lane >> 3);
  const __bf16* Asrc = A  + (size_t)(row0 + srow) * Kd + schunk * 8;
  const __bf16* Bsrc = Bm + (size_t)(col0 + srow) * Kd + schunk * 8;

  // ds_read bases, chunk swizzled by row&7 = l16&7
  const int c0    = (qd ^ (l16 & 7)) * 8;
  const int aoff0 = (wm * 128 + l16) * 64 + c0;           // i=0, kk=0
  const int boff0 = 16384 + (wn * 64 + l16) * 64 + c0;    // j=0, kk=0

  f32x4 acc[8][4];
  #pragma unroll
  for (int i = 0; i < 8; i++)
    #pragma unroll
    for (int j = 0; j < 4; j++)
      acc[i][j] = (f32x4){0.f, 0.f, 0.f, 0.f};

  bf16x8 a0[4][2], a1[4][2], b0[2][2], b1[2][2];

  STAGE_AH_AT(0, 0, 0); STAGE_AH_AT(0, 1, 0);
  STAGE_BH_AT(0, 0, 0); STAGE_BH_AT(0, 1, 0);
  STAGE_BH_AT(32768, 0, 1); STAGE_BH_AT(32768, 1, 1);
  WAITV(4);
  BARX();
  SCHEDB();

  const int ntile = Kd >> 6;       // 32
  #pragma unroll 1
  for (int it = 0; it < (ntile - 2) / 2; ++it) {
    const int t = it << 1;
    TILE_BODY(0,     32768, t + 1, t + 2);
    TILE_BODY(32768, 0,     t + 2, t + 3);
  }

  {
    RD_A0(0); RD_B0(0); RD_B1(0);
    STAGE_AH_AT(32768, 0, ntile - 1); STAGE_AH_AT(32768, 1, ntile - 1);
    __builtin_amdgcn_s_setprio(1);
    MFMA16(a0, b0, 0, 0);
    MFMA16(a0, b1, 0, 2);
    __builtin_amdgcn_s_setprio(0);
    SCHEDB();
    RD_A1(0);
    __builtin_amdgcn_s_setprio(1);
    MFMA16(a1, b1, 4, 2);
    MFMA16(a1, b0, 4, 0);
    __builtin_amdgcn_s_setprio(0);
    WAITV(0);
    BARX();
    SCHEDB();
  }
  {
    RD_A0(32768); RD_B0(32768); RD_B1(32768);
    __builtin_amdgcn_s_setprio(1);
    MFMA16(a0, b0, 0, 0);
    MFMA16(a0, b1, 0, 2);
    __builtin_amdgcn_s_setprio(0);
    SCHEDB();
    RD_A1(32768);
    __builtin_amdgcn_s_setprio(1);
    MFMA16(a1, b1, 4, 2);
    MFMA16(a1, b0, 4, 0);
    __builtin_amdgcn_s_setprio(0);
  }

  // epilogue: C/D layout col=lane&15, row=quad*4+reg (verified m89/m91)
  #pragma unroll
  for (int i = 0; i < 8; i++) {
    const int rb = row0 + wm * 128 + i * 16 + qd * 4;
    #pragma unroll
    for (int j = 0; j < 4; j++) {
      const int c = col0 + wn * 64 + j * 16 + l16;
      #pragma unroll
      for (int reg = 0; reg < 4; reg++) {
        const size_t idx = (size_t)(rb + reg) * Nd + c;
        float v = acc[i][j][reg];
        if (EPI == 0) {
          ((float*)Cout)[idx] = v;
        } else if (EPI == 1) {
          if (isf32) ((float*)Cout)[idx] = v;
          else       ((__bf16*)Cout)[idx] = (__bf16)v;
        } else if (EPI == 3) {
          ((__bf16*)Cout)[idx] = (__bf16)v;
        } else {
          float s = 1.f / (1.f + __expf(-v));
          ((__bf16*)Cout)[idx] = (__bf16)s;
        }
      }
    }
  }
}

// ---------------------------------------------------------------------------
// WKV parallel log-sum-exp prefix sum. Round 9: 2-wide per thread (float2 k,
// bf16x2 v) for 2x bytes/instruction; Wkv output now bf16 (post-division
// O(1) values; LN stats average bf16 noise).
// ---------------------------------------------------------------------------
__global__ void wkv_part_kernel(const float* __restrict__ Kb,
                                const __bf16* __restrict__ Vb,
                                float* __restrict__ pM,
                                float* __restrict__ pA,
                                float* __restrict__ pB)
{
  const int gid = blockIdx.x * blockDim.x + threadIdx.x;  // 0..B*WC*D/2-1
  const int d = (gid & (DD / 2 - 1)) * 2;
  const int rest = gid >> 10;
  const int c = rest & (WC - 1);
  const int b = rest >> 6;
  const float*  kp = Kb + ((size_t)b * TT + (size_t)c * WL) * DD + d;
  const __bf16* vp = Vb + ((size_t)b * TT + (size_t)c * WL) * DD + d;
  float M0 = -1e38f, A0 = 0.f, B0 = 0.f;
  float M1 = -1e38f, A1 = 0.f, B1 = 0.f;
  for (int t = 0; t < WL; t++) {
    const float2 k2 = *(const float2*)(kp + (size_t)t * DD);
    const bf16x2 v2 = *(const bf16x2*)(vp + (size_t)t * DD);
    {
      const float q = fmaxf(M0, k2.x);
      const float s = __expf(M0 - q);
      const float e = __expf(k2.x - q);
      A0 = A0 * s + e * (float)v2[0];
      B0 = B0 * s + e;
      M0 = q;
    }
    {
      const float q = fmaxf(M1, k2.y);
      const float s = __expf(M1 - q);
      const float e = __expf(k2.y - q);
      A1 = A1 * s + e * (float)v2[1];
      B1 = B1 * s + e;
      M1 = q;
    }
  }
  const size_t pi = ((size_t)b * WC + c) * DD + d;
  *(float2*)(pM + pi) = make_float2(M0, M1);
  *(float2*)(pA + pi) = make_float2(A0, A1);
  *(float2*)(pB + pi) = make_float2(B0, B1);
}

__global__ void wkv_scan_kernel(float* __restrict__ pM,
                                float* __restrict__ pA,
                                float* __restrict__ pB)
{
  const int gid = blockIdx.x * blockDim.x + threadIdx.x;  // 0..B*D/2-1
  const int d = (gid & (DD / 2 - 1)) * 2;
  const int b = gid >> 10;
  float M0 = -1e38f, A0 = 0.f, B0 = 0.f;
  float M1 = -1e38f, A1 = 0.f, B1 = 0.f;
  for (int c = 0; c < WC; c++) {
    const size_t pi = ((size_t)b * WC + c) * DD + d;
    const float2 m2 = *(const float2*)(pM + pi);
    const float2 a2 = *(const float2*)(pA + pi);
    const float2 b2 = *(const float2*)(pB + pi);
    *(float2*)(pM + pi) = make_float2(M0, M1);
    *(float2*)(pA + pi) = make_float2(A0, A1);
    *(float2*)(pB + pi) = make_float2(B0, B1);
    {
      const float q = fmaxf(M0, m2.x);
      const float s0 = __expf(M0 - q);
      const float s1 = __expf(m2.x - q);
      A0 = A0 * s0 + a2.x * s1;
      B0 = B0 * s0 + b2.x * s1;
      M0 = q;
    }
    {
      const float q = fmaxf(M1, m2.y);
      const float s0 = __expf(M1 - q);
      const float s1 = __expf(m2.y - q);
      A1 = A1 * s0 + a2.y * s1;
      B1 = B1 * s0 + b2.y * s1;
      M1 = q;
    }
  }
}

__global__ void wkv_out_kernel(const float* __restrict__ Kb,
                               const __bf16* __restrict__ Vb,
                               const float* __restrict__ pM,
                               const float* __restrict__ pA,
                               const float* __restrict__ pB,
                               const float* __restrict__ tfirstF,
                               __bf16* __restrict__ out)
{
  const int gid = blockIdx.x * blockDim.x + threadIdx.x;
  const int d = (gid & (DD / 2 - 1)) * 2;
  const int rest = gid >> 10;
  const int c = rest & (WC - 1);
  const int b = rest >> 6;
  const size_t pi = ((size_t)b * WC + c) * DD + d;
  float2 M2 = *(const float2*)(pM + pi);
  float2 A2 = *(const float2*)(pA + pi);
  float2 B2 = *(const float2*)(pB + pi);
  float M0 = M2.x, A0 = A2.x, B0 = B2.x;
  float M1 = M2.y, A1 = A2.y, B1 = B2.y;
  const float u0 = tfirstF[d];
  const float u1 = tfirstF[d + 1];
  const size_t base = ((size_t)b * TT + (size_t)c * WL) * DD + d;
  const float*  kp = Kb + base;
  const __bf16* vp = Vb + base;
  __bf16*       op = out + base;
  for (int t = 0; t < WL; t++) {
    const float2 k2 = *(const float2*)(kp + (size_t)t * DD);
    const bf16x2 v2 = *(const bf16x2*)(vp + (size_t)t * DD);
    bf16x2 o2;
    {
      const float v = (float)v2[0];
      const float ku = k2.x + u0;
      const float qo = fmaxf(M0, ku);
      const float so = __expf(M0 - qo);
      const float eo = __expf(ku - qo);
      o2[0] = (__bf16)__fdividef(A0 * so + v * eo, B0 * so + eo);
      const float q = fmaxf(M0, k2.x);
      const float s = __expf(M0 - q);
      const float e = __expf(k2.x - q);
      A0 = A0 * s + e * v;
      B0 = B0 * s + e;
      M0 = q;
    }
    {
      const float v = (float)v2[1];
      const float ku = k2.y + u1;
      const float qo = fmaxf(M1, ku);
      const float so = __expf(M1 - qo);
      const float eo = __expf(ku - qo);
      o2[1] = (__bf16)__fdividef(A1 * so + v * eo, B1 * so + eo);
      const float q = fmaxf(M1, k2.y);
      const float s = __expf(M1 - q);
      const float e = __expf(k2.y - q);
      A1 = A1 * s + e * v;
      B1 = B1 * s + e;
      M1 = q;
    }
    *(bf16x2*)(op + (size_t)t * DD) = o2;
  }
}

// ---------------------------------------------------------------------------
// Kernel 4: LayerNorm over D + multiply by r -> rwkv (bf16). Round 9:
// bf16 wkv input, 8-consecutive-element vectorized loads/stores (16 B/lane).
// ---------------------------------------------------------------------------
__global__ void ln_kernel(const __bf16* __restrict__ wkv,
                          const __bf16* __restrict__ rbuf,
                          const float* __restrict__ g,
                          const float* __restrict__ beta,
                          __bf16* __restrict__ out)
{
  const int row = blockIdx.x;
  const int tid = threadIdx.x;
  const size_t base = (size_t)row * DD + (size_t)tid * 8;

  bf16x8 w8 = *(const bf16x8*)(wkv + base);
  float vals[8];
  float s = 0.f, sq = 0.f;
  #pragma unroll
  for (int e = 0; e < 8; e++) {
    const float v = (float)w8[e];
    vals[e] = v;
    s += v;
    sq += v * v;
  }
  #pragma unroll
  for (int off = 1; off < 64; off <<= 1) {
    s  += __shfl_xor(s, off);
    sq += __shfl_xor(sq, off);
  }
  __shared__ float ls[4], lsq[4];
  const int wave = tid >> 6;
  if ((tid & 63) == 0) { ls[wave] = s; lsq[wave] = sq; }
  __syncthreads();
  s  = ls[0] + ls[1] + ls[2] + ls[3];
  sq = lsq[0] + lsq[1] + lsq[2] + lsq[3];

  const float mu = s * (1.f / DD);
  const float var = sq * (1.f / DD) - mu * mu;
  const float rs = rsqrtf(var + 1e-5f);

  bf16x8 r8 = *(const bf16x8*)(rbuf + base);
  f32x4 g0 = *(const f32x4*)(g + tid * 8);
  f32x4 g1 = *(const f32x4*)(g + tid * 8 + 4);
  f32x4 be0 = *(const f32x4*)(beta + tid * 8);
  f32x4 be1 = *(const f32x4*)(beta + tid * 8 + 4);

  bf16x8 o8;
  #pragma unroll
  for (int e = 0; e < 4; e++) {
    const float v0 = (vals[e] - mu) * rs * g0[e] + be0[e];
    const float v1 = (vals[e + 4] - mu) * rs * g1[e] + be1[e];
    o8[e]     = (__bf16)((float)r8[e]     * v0);
    o8[e + 4] = (__bf16)((float)r8[e + 4] * v1);
  }
  *(bf16x8*)(out + base) = o8;
}

// ---------------------------------------------------------------------------
extern "C" void kernel_launch(void* const* d_in, const int* in_sizes, int n_in,
                              void* d_out, int out_size, void* d_ws, size_t ws_size,
                              hipStream_t stream) {
  const void* x      = d_in[0];
  const void* Wk     = d_in[1];
  const void* Wv     = d_in[2];
  const void* Wr     = d_in[3];
  const void* Wo     = d_in[4];
  const void* tmk    = d_in[5];
  const void* tmv    = d_in[6];
  const void* tmr    = d_in[7];
  const void* tdec   = d_in[8];
  const void* tfirst = d_in[9];
  const void* lng    = d_in[10];
  const void* lnb    = d_in[11];

  char* ws = (char*)d_ws;
  const size_t SZ_BF = (size_t)MM * DD * 2;   // 64 MiB
  const size_t SZ_F  = (size_t)MM * DD * 4;   // 128 MiB
  const size_t SZ_W  = (size_t)DD * DD * 2;   // 8 MiB
  __bf16* XK   = (__bf16*)(ws);
  __bf16* XV   = (__bf16*)(ws + SZ_BF);
  __bf16* XR   = (__bf16*)(ws + 2 * SZ_BF);
  float*  Kb   = (float*)(ws + 3 * SZ_BF);
  __bf16* Vb   = (__bf16*)(ws + 3 * SZ_BF + SZ_F);   // bf16 (region reused)
  __bf16* WkB  = (__bf16*)(ws + 3 * SZ_BF + 2 * SZ_F);
  __bf16* WvB  = (__bf16*)(ws + 3 * SZ_BF + 2 * SZ_F + SZ_W);
  __bf16* WrB  = (__bf16*)(ws + 3 * SZ_BF + 2 * SZ_F + 2 * SZ_W);
  __bf16* WoB  = (__bf16*)(ws + 3 * SZ_BF + 2 * SZ_F + 3 * SZ_W);
  char*   smal = ws + 3 * SZ_BF + 2 * SZ_F + 4 * SZ_W;
  int*    flag    = (int*)smal;
  float*  tdecF   = (float*)(smal + 64);
  float*  tfirstF = tdecF + DD;
  float*  lngF    = tdecF + 2 * DD;
  float*  lnbF    = tdecF + 3 * DD;
  float*  tmkF    = tdecF + 4 * DD;
  float*  tmvF    = tdecF + 5 * DD;
  float*  tmrF    = tdecF + 6 * DD;
  __bf16* Wkv  = (__bf16*)(ws);                // bf16 now; over XK (dead)
  __bf16* Rwkv = (__bf16*)(ws + 2 * SZ_BF);    // over XR
  __bf16* Rb   = (__bf16*)d_out;               // d_out as scratch until final GEMM
  float* pM = (float*)(ws + 2 * SZ_BF);
  float* pA = pM + (size_t)BB * WC * DD;
  float* pB = pA + (size_t)BB * WC * DD;

  detect_small_kernel<<<dim3(1), dim3(256), 0, stream>>>(
      tdec, tfirst, lng, lnb, tmk, tmv, tmr,
      flag, tdecF, tfirstF, lngF, lnbF, tmkF, tmvF, tmrF);

  convert_w_kernel<<<dim3(512), dim3(256), 0, stream>>>(Wk, WkB, flag);
  convert_w_kernel<<<dim3(512), dim3(256), 0, stream>>>(Wv, WvB, flag);
  convert_w_kernel<<<dim3(512), dim3(256), 0, stream>>>(Wr, WrB, flag);
  convert_w_kernel<<<dim3(512), dim3(256), 0, stream>>>(Wo, WoB, flag);

  mix_kernel<<<dim3(4096), dim3(256), 0, stream>>>(x, tmkF, tmvF, tmrF, flag, XK, XV, XR);

  dim3 g(512), blk(512);   // 256x256 tiles; A-reuse XCD map inside kernel
  gemm_bt<0><<<g, blk, 0, stream>>>(XK, WkB, (void*)Kb, flag, MM, DD, DD);
  gemm_bt<3><<<g, blk, 0, stream>>>(XV, WvB, (void*)Vb, flag, MM, DD, DD);
  gemm_bt<2><<<g, blk, 0, stream>>>(XR, WrB, (void*)Rb, flag, MM, DD, DD);

  // 2-wide wkv: B*WC*D/2 = 262144 threads -> 1024 blocks; scan 16 blocks
  wkv_part_kernel<<<dim3(1024), dim3(256), 0, stream>>>(Kb, Vb, pM, pA, pB);
  wkv_scan_kernel<<<dim3(16), dim3(256), 0, stream>>>(pM, pA, pB);
  wkv_out_kernel<<<dim3(1024), dim3(256), 0, stream>>>(Kb, Vb, pM, pA, pB, tfirstF, Wkv);

  ln_kernel<<<dim3(MM), dim3(256), 0, stream>>>(Wkv, Rb, lngF, lnbF, Rwkv);

  gemm_bt<1><<<g, blk, 0, stream>>>(Rwkv, WoB, d_out, flag, MM, DD, DD);
}